// Round 5
// baseline (14018.509 us; speedup 1.0000x reference)
//
#include <hip/hip_runtime.h>
#include <hip/hip_fp16.h>

#define B_   64
#define T_   512
#define DINc 512
#define D_   512
#define NWG  16
#define JS   32   // output columns per workgroup in scan

typedef _Float16 half8 __attribute__((ext_vector_type(8)));
typedef _Float16 half4 __attribute__((ext_vector_type(4)));
typedef float   floatx4 __attribute__((ext_vector_type(4)));
typedef unsigned long long ullx2 __attribute__((ext_vector_type(2)));

// ---------------- X convert + transpose: Xh[m][k] = (f16) X[b][t][k], m = t*64+b ----------------
__global__ __launch_bounds__(256) void k_cvtX(const float* __restrict__ X, _Float16* __restrict__ Xh) {
    int idx = blockIdx.x * 256 + threadIdx.x;
    int m  = idx >> 6;
    int k8 = idx & 63;
    int b = m & 63, t = m >> 6;
    const float* src = X + ((size_t)(b * T_ + t)) * DINc + k8 * 8;
    float4 f0 = *(const float4*)(src);
    float4 f1 = *(const float4*)(src + 4);
    half8 h;
    h[0] = (_Float16)f0.x; h[1] = (_Float16)f0.y; h[2] = (_Float16)f0.z; h[3] = (_Float16)f0.w;
    h[4] = (_Float16)f1.x; h[5] = (_Float16)f1.y; h[6] = (_Float16)f1.z; h[7] = (_Float16)f1.w;
    *(half8*)(Xh + (size_t)m * DINc + k8 * 8) = h;
}

// ---------------- W transpose + convert: Wt[g][n][k] = (f16) W_g[k][n] ----------------
__global__ __launch_bounds__(256) void k_cvtW(const float* __restrict__ Wz, const float* __restrict__ Wr,
                                              const float* __restrict__ Wh, _Float16* __restrict__ Wt) {
    __shared__ float tile[64][65];
    int g = blockIdx.z;
    const float* W = (g == 0) ? Wz : ((g == 1) ? Wr : Wh);
    int n0 = blockIdx.x * 64, k0 = blockIdx.y * 64;
    int c = threadIdx.x & 63, r4 = threadIdx.x >> 6;
#pragma unroll
    for (int i = 0; i < 16; ++i) {
        int k = r4 + i * 4;
        tile[k][c] = W[(size_t)(k0 + k) * D_ + n0 + c];
    }
    __syncthreads();
    _Float16* out = Wt + (size_t)g * D_ * DINc;
#pragma unroll
    for (int i = 0; i < 16; ++i) {
        int n = r4 + i * 4;
        out[(size_t)(n0 + n) * DINc + k0 + c] = (_Float16)tile[c][n];
    }
}

// ---------------- mask transpose: maskT[t][b] = (float) mask[b][t] ----------------
__global__ __launch_bounds__(256) void k_cvtM(const int* __restrict__ mask, float* __restrict__ maskT) {
    int idx = blockIdx.x * 256 + threadIdx.x;   // 32768
    int t = idx >> 6, b = idx & 63;
    maskT[idx] = (float)mask[(size_t)b * T_ + t];
}

// ---- input projections: xprojT[g][t][n][b] = (Xh[m] @ W_g)[n] + b_g[n], m=t*64+b (f16) ----
__global__ __launch_bounds__(256) void k_gemm(const _Float16* __restrict__ Xh, const _Float16* __restrict__ Wt,
                                              const float* __restrict__ bz, const float* __restrict__ br,
                                              const float* __restrict__ bh, _Float16* __restrict__ xprojT) {
    __shared__ _Float16 As[128 * 32];
    __shared__ _Float16 Bs[128 * 32];
    int g = blockIdx.z;
    const _Float16* Wg = Wt + (size_t)g * 512 * 512;
    const float* bias = (g == 0) ? bz : ((g == 1) ? br : bh);
    _Float16* out = xprojT + (size_t)g * 16777216;
    int mb = blockIdx.x * 128, nb = blockIdx.y * 128;
    int tid = threadIdx.x, l = tid & 63, w = tid >> 6;
    int wr = w >> 1, wc = w & 1;
    int lr = l & 15, lg = l >> 4;

    floatx4 acc[4][4] = {};

    int ga0 = tid, ga1 = tid + 256;
    int ra0 = ga0 >> 2, ca0 = (ga0 & 3) * 8;
    int ra1 = ga1 >> 2, ca1 = (ga1 & 3) * 8;

    uint4 pa0, pa1, pb0, pb1;
    pa0 = *(const uint4*)(Xh + (size_t)(mb + ra0) * 512 + ca0);
    pa1 = *(const uint4*)(Xh + (size_t)(mb + ra1) * 512 + ca1);
    pb0 = *(const uint4*)(Wg + (size_t)(nb + ra0) * 512 + ca0);
    pb1 = *(const uint4*)(Wg + (size_t)(nb + ra1) * 512 + ca1);

    for (int kt = 0; kt < 16; ++kt) {
        __syncthreads();
        *(uint4*)(&As[ga0 * 8]) = pa0;
        *(uint4*)(&As[ga1 * 8]) = pa1;
        *(uint4*)(&Bs[ga0 * 8]) = pb0;
        *(uint4*)(&Bs[ga1 * 8]) = pb1;
        __syncthreads();
        if (kt < 15) {
            int kb = (kt + 1) * 32;
            pa0 = *(const uint4*)(Xh + (size_t)(mb + ra0) * 512 + kb + ca0);
            pa1 = *(const uint4*)(Xh + (size_t)(mb + ra1) * 512 + kb + ca1);
            pb0 = *(const uint4*)(Wg + (size_t)(nb + ra0) * 512 + kb + ca0);
            pb1 = *(const uint4*)(Wg + (size_t)(nb + ra1) * 512 + kb + ca1);
        }
        half8 af[4], bf[4];
#pragma unroll
        for (int mi = 0; mi < 4; mi++) af[mi] = *(const half8*)(&As[(wr * 64 + mi * 16 + lr) * 32 + lg * 8]);
#pragma unroll
        for (int ni = 0; ni < 4; ni++) bf[ni] = *(const half8*)(&Bs[(wc * 64 + ni * 16 + lr) * 32 + lg * 8]);
#pragma unroll
        for (int mi = 0; mi < 4; mi++)
#pragma unroll
            for (int ni = 0; ni < 4; ni++)
                acc[mi][ni] = __builtin_amdgcn_mfma_f32_16x16x32_f16(af[mi], bf[ni], acc[mi][ni], 0, 0, 0);
    }

#pragma unroll
    for (int ni = 0; ni < 4; ni++) {
        int col = nb + wc * 64 + ni * 16 + lr;
        float bv = bias[col];
#pragma unroll
        for (int mi = 0; mi < 4; mi++) {
            int row = mb + wr * 64 + mi * 16 + lg * 4;   // global m; b = row&63, t = row>>6
            int tt = row >> 6, bb = row & 63;
            half4 hv;
#pragma unroll
            for (int i = 0; i < 4; i++) hv[i] = (_Float16)(acc[mi][ni][i] + bv);
            *(half4*)(out + (size_t)tt * 32768 + (size_t)col * 64 + bb) = hv;
        }
    }
}

// -------- agent-scope (device-coherent) atomic helpers — PROVEN path (Round 2) --------
__device__ __forceinline__ unsigned long long ld_agent(const unsigned long long* p) {
    return __hip_atomic_load(p, __ATOMIC_RELAXED, __HIP_MEMORY_SCOPE_AGENT);
}
__device__ __forceinline__ void st_agent(unsigned long long* p, unsigned long long v) {
    __hip_atomic_store(p, v, __ATOMIC_RELAXED, __HIP_MEMORY_SCOPE_AGENT);
}
__device__ __forceinline__ unsigned ld_flag(const unsigned* p) {
    return __hip_atomic_load(p, __ATOMIC_RELAXED, __HIP_MEMORY_SCOPE_AGENT);
}
__device__ __forceinline__ void st_flag(unsigned* p, unsigned v) {
    __hip_atomic_store(p, v, __ATOMIC_RELAXED, __HIP_MEMORY_SCOPE_AGENT);
}

// pack this thread's 4 fp32 values (4 rows, 1 col) into the 8B row-major unit
// (1 row, 4 cols) for its assigned row (lr&3), via 2-round shfl_xor butterfly
__device__ __forceinline__ unsigned long long pack_quad(const float v4[4], int lr) {
    unsigned long long unit = 0;
    int j = lr & 3;
#pragma unroll
    for (int i = 0; i < 4; i++) {
        _Float16 hv = (_Float16)v4[i];
        unsigned int v = (unsigned int)__builtin_bit_cast(unsigned short, hv);
        unsigned int o1 = __shfl_xor(v, 1, 64);
        unsigned int pair = (lr & 1) ? (o1 | (v << 16)) : (v | (o1 << 16));
        unsigned int q2 = __shfl_xor(pair, 2, 64);
        unsigned long long u = (lr & 2) ? ((unsigned long long)q2 | ((unsigned long long)pair << 32))
                                        : ((unsigned long long)pair | ((unsigned long long)q2 << 32));
        if (i == j) unit = u;
    }
    return unit;
}

// wave-parallel wait with backoff: lanes 0..15 each watch one WG's flag.
// s_sleep(1) keeps the aggregate agent-scope request rate low so the
// publishers' flag STORES aren't starved (R4 post-mortem).
__device__ __forceinline__ void wait_all_flags(const unsigned* f, unsigned need, int l) {
    for (;;) {
        unsigned v = (l < NWG) ? ld_flag(f + l * 16) : need;
        if (__all(v >= need)) break;
        __builtin_amdgcn_s_sleep(1);
    }
    __builtin_amdgcn_sched_barrier(0);
}

// ---------------- recurrent scan: 16 WGs x 512 threads, each owns JS=32 columns ----------------
__global__ __launch_bounds__(512) void k_scan(const float* __restrict__ Uz, const float* __restrict__ Ur,
                                              const float* __restrict__ Uh, const float* __restrict__ maskT,
                                              const _Float16* __restrict__ xprojT,
                                              unsigned long long* __restrict__ hbuf,   // [2][64][512] f16, 8B units
                                              unsigned long long* __restrict__ rhbuf,  // [2][64][512] f16, 8B units
                                              unsigned* __restrict__ fh, unsigned* __restrict__ fr,
                                              float* __restrict__ out) {
    __shared__ _Float16 Ulds[3 * JS * 512];   // 96KB: [gate][n 32][k 512], XOR-swizzled 16B granules
    int tid = threadIdx.x, l = tid & 63, w = tid >> 6;
    int lr = l & 15, lg = l >> 4;
    int mt = w >> 1, nt = w & 1;              // wave's (M,N) 16x16 tile
    int slot = blockIdx.x;
    int jsb = slot * JS;

    // ---- stage U slices into LDS (transposed + swizzled), fp32 -> fp16 ----
    for (int idx = tid; idx < JS * 512; idx += 512) {
        int n = idx & (JS - 1);
        int k = idx >> 5;
        int byte_off = n * 1024 + ((k * 2) ^ ((n & 7) << 4));
        *(_Float16*)((char*)Ulds + byte_off)         = (_Float16)Uz[(size_t)k * D_ + jsb + n];
        *(_Float16*)((char*)Ulds + 32768 + byte_off) = (_Float16)Ur[(size_t)k * D_ + jsb + n];
        *(_Float16*)((char*)Ulds + 65536 + byte_off) = (_Float16)Uh[(size_t)k * D_ + jsb + n];
    }
    __syncthreads();

    const char* UB = (const char*)Ulds + (nt * 16 + lr) * 1024;  // B-fragment row base (col = nt*16+lr)
    const int swz = (lr & 7) << 4;

    int row0 = mt * 16 + lg * 4;              // this thread's 4 C-rows (batch)
    int colg = jsb + nt * 16 + lr;            // this thread's C-col (global hidden index)

    float h4[4]  = {0.f, 0.f, 0.f, 0.f};
    float hm4[4] = {0.f, 0.f, 0.f, 0.f};

    const int punit = (mt * 16 + lg * 4 + (lr & 3)) * 128 + ((jsb + nt * 16) >> 2) + ((lr >> 2) & 3);
    const int gbase = (mt * 16 + lr) * 128 + lg * 2;
    const int jrot  = (slot * 2) & 15;        // stagger gather line order across WGs

    const _Float16* xzB = xprojT + (size_t)colg * 64 + row0;
    const _Float16* xrB = xzB + (size_t)16777216;
    const _Float16* xhB = xrB + (size_t)16777216;

    // ---------------- step 0: no gather (hm = 0) ----------------
    {
        half4 xz0 = *(const half4*)(xzB);
        half4 xh0 = *(const half4*)(xhB);
        float4 m0 = *(const float4*)(maskT + row0);
#pragma unroll
        for (int i = 0; i < 4; i++) {
            float z  = 1.f / (1.f + __expf(-(float)xz0[i]));
            float hh = tanhf((float)xh0[i]);
            h4[i]  = (1.f - z) * hh;
            hm4[i] = ((float)m0[i]) * h4[i];
        }
        st_agent(hbuf + 0 * 8192 + punit, pack_quad(hm4, lr));
        asm volatile("s_waitcnt vmcnt(0)" ::: "memory");
        __syncthreads();
        if (tid == 0) st_flag(fh + slot * 16, 1u);
    }

    for (int t = 1; t < T_; ++t) {
        const unsigned long long* hmG = hbuf + ((t - 1) & 1) * 8192;
        unsigned long long* rhW       = rhbuf + (t & 1) * 8192;
        unsigned long long* hW        = hbuf + (t & 1) * 8192;

        // issue this step's x loads early (hidden under the flag wait)
        half4 xzp = *(const half4*)(xzB + (size_t)t * 32768);
        half4 xrp = *(const half4*)(xrB + (size_t)t * 32768);
        half4 xhp = *(const half4*)(xhB + (size_t)t * 32768);
        float4 mv = *(const float4*)(maskT + (size_t)t * 64 + row0);

        // ---- phase 1: wait h_{t-1}, gather, z/r MFMAs ----
        wait_all_flags(fh, (unsigned)t, l);
        half8 af[16];
#pragma unroll
        for (int j2 = 0; j2 < 16; j2++) {
            int j = (j2 + jrot) & 15;
            ullx2 u;
            u[0] = ld_agent(hmG + gbase + j * 8);
            u[1] = ld_agent(hmG + gbase + j * 8 + 1);
            af[j] = __builtin_bit_cast(half8, u);
        }
        floatx4 accz = {0.f, 0.f, 0.f, 0.f}, accr = {0.f, 0.f, 0.f, 0.f};
#pragma unroll
        for (int j = 0; j < 16; j++) {
            int boff = (j * 64 + lg * 16) ^ swz;
            half8 bz8 = *(const half8*)(UB + boff);
            half8 br8 = *(const half8*)(UB + 32768 + boff);
            accz = __builtin_amdgcn_mfma_f32_16x16x32_f16(af[j], bz8, accz, 0, 0, 0);
            accr = __builtin_amdgcn_mfma_f32_16x16x32_f16(af[j], br8, accr, 0, 0, 0);
        }
        float z4[4], rh4[4];
#pragma unroll
        for (int i = 0; i < 4; i++) {
            float zz = 1.f / (1.f + __expf(-((float)xzp[i] + accz[i])));
            float rr = 1.f / (1.f + __expf(-((float)xrp[i] + accr[i])));
            z4[i]  = zz;
            rh4[i] = rr * hm4[i];
        }
        st_agent(rhW + punit, pack_quad(rh4, lr));
        asm volatile("s_waitcnt vmcnt(0)" ::: "memory");
        __syncthreads();
        if (tid == 0) st_flag(fr + slot * 16, (unsigned)t);

        // ---- phase 2: wait rh_t, gather, candidate MFMAs, state update ----
        wait_all_flags(fr, (unsigned)t, l);
        half8 af2[16];
#pragma unroll
        for (int j2 = 0; j2 < 16; j2++) {
            int j = (j2 + jrot) & 15;
            ullx2 u;
            u[0] = ld_agent(rhW + gbase + j * 8);
            u[1] = ld_agent(rhW + gbase + j * 8 + 1);
            af2[j] = __builtin_bit_cast(half8, u);
        }
        floatx4 acch0 = {0.f, 0.f, 0.f, 0.f}, acch1 = {0.f, 0.f, 0.f, 0.f};
#pragma unroll
        for (int j = 0; j < 16; j += 2) {
            int b0 = (j * 64 + lg * 16) ^ swz;
            int b1 = ((j + 1) * 64 + lg * 16) ^ swz;
            half8 bh8a = *(const half8*)(UB + 65536 + b0);
            half8 bh8b = *(const half8*)(UB + 65536 + b1);
            acch0 = __builtin_amdgcn_mfma_f32_16x16x32_f16(af2[j],     bh8a, acch0, 0, 0, 0);
            acch1 = __builtin_amdgcn_mfma_f32_16x16x32_f16(af2[j + 1], bh8b, acch1, 0, 0, 0);
        }
#pragma unroll
        for (int i = 0; i < 4; i++) {
            float hh = tanhf((float)xhp[i] + acch0[i] + acch1[i]);
            h4[i]  = z4[i] * hm4[i] + (1.f - z4[i]) * hh;
            hm4[i] = ((float)mv[i]) * h4[i];
        }
        st_agent(hW + punit, pack_quad(hm4, lr));
        asm volatile("s_waitcnt vmcnt(0)" ::: "memory");
        __syncthreads();
        if (tid == 0) st_flag(fh + slot * 16, (unsigned)(t + 1));
    }

#pragma unroll
    for (int i = 0; i < 4; i++)
        out[(size_t)(row0 + i) * 512 + colg] = h4[i];
}

extern "C" void kernel_launch(void* const* d_in, const int* in_sizes, int n_in,
                              void* d_out, int out_size, void* d_ws, size_t ws_size,
                              hipStream_t stream) {
    (void)in_sizes; (void)n_in; (void)out_size; (void)ws_size;
    const float* X  = (const float*)d_in[0];
    const float* Wz = (const float*)d_in[1];
    const float* Uz = (const float*)d_in[2];
    const float* bz = (const float*)d_in[3];
    const float* Wr = (const float*)d_in[4];
    const float* Ur = (const float*)d_in[5];
    const float* br = (const float*)d_in[6];
    const float* Wh = (const float*)d_in[7];
    const float* Uh = (const float*)d_in[8];
    const float* bh = (const float*)d_in[9];
    const int* mask = (const int*)d_in[10];
    float* out = (float*)d_out;

    char* ws = (char*)d_ws;
    unsigned* fh = (unsigned*)ws;                                    // 1KB (16 flags, 64B stride)
    unsigned* fr = (unsigned*)(ws + 1024);                           // 1KB
    unsigned long long* hbuf  = (unsigned long long*)(ws + 8192);              // 128KB
    unsigned long long* rhbuf = (unsigned long long*)(ws + 8192 + 131072);     // 128KB
    _Float16* Xh     = (_Float16*)(ws + 8192 + 2 * 131072);                    // 32MB
    _Float16* Wt     = (_Float16*)(ws + 8192 + 2 * 131072 + 33554432);         // 1.5MB
    _Float16* xprojT = (_Float16*)(ws + 8192 + 2 * 131072 + 33554432 + 1572864);   // 96MB
    float*    maskT  = (float*)(ws + 8192 + 2 * 131072 + 33554432 + 1572864 + 100663296); // 128KB

    hipMemsetAsync(ws, 0, 8192, stream);
    hipLaunchKernelGGL(k_cvtX, dim3(8192), dim3(256), 0, stream, X, Xh);
    hipLaunchKernelGGL(k_cvtW, dim3(8, 8, 3), dim3(256), 0, stream, Wz, Wr, Wh, Wt);
    hipLaunchKernelGGL(k_cvtM, dim3(128), dim3(256), 0, stream, mask, maskT);
    hipLaunchKernelGGL(k_gemm, dim3(256, 4, 3), dim3(256), 0, stream, Xh, Wt, bz, br, bh, xprojT);
    hipLaunchKernelGGL(k_scan, dim3(NWG), dim3(512), 0, stream, Uz, Ur, Uh, maskT, xprojT,
                       hbuf, rhbuf, fh, fr, out);
}

// Round 6
// 4306.746 us; speedup vs baseline: 3.2550x; 3.2550x over previous
//
#include <hip/hip_runtime.h>
#include <hip/hip_fp16.h>

#define B_   64
#define T_   512
#define DINc 512
#define D_   512
#define NWG  16
#define JS   32   // output columns per workgroup in scan

typedef _Float16 half8 __attribute__((ext_vector_type(8)));
typedef _Float16 half4 __attribute__((ext_vector_type(4)));
typedef float   floatx4 __attribute__((ext_vector_type(4)));
typedef unsigned uintx4 __attribute__((ext_vector_type(4)));

// ---------------- X convert + transpose: Xh[m][k] = (f16) X[b][t][k], m = t*64+b ----------------
__global__ __launch_bounds__(256) void k_cvtX(const float* __restrict__ X, _Float16* __restrict__ Xh) {
    int idx = blockIdx.x * 256 + threadIdx.x;
    int m  = idx >> 6;
    int k8 = idx & 63;
    int b = m & 63, t = m >> 6;
    const float* src = X + ((size_t)(b * T_ + t)) * DINc + k8 * 8;
    float4 f0 = *(const float4*)(src);
    float4 f1 = *(const float4*)(src + 4);
    half8 h;
    h[0] = (_Float16)f0.x; h[1] = (_Float16)f0.y; h[2] = (_Float16)f0.z; h[3] = (_Float16)f0.w;
    h[4] = (_Float16)f1.x; h[5] = (_Float16)f1.y; h[6] = (_Float16)f1.z; h[7] = (_Float16)f1.w;
    *(half8*)(Xh + (size_t)m * DINc + k8 * 8) = h;
}

// ---------------- generic 3-matrix transpose + convert: Mt[g][n][k] = (f16) M_g[k][n] ----------------
__global__ __launch_bounds__(256) void k_cvtW(const float* __restrict__ M0, const float* __restrict__ M1,
                                              const float* __restrict__ M2, _Float16* __restrict__ Mt) {
    __shared__ float tile[64][65];
    int g = blockIdx.z;
    const float* W = (g == 0) ? M0 : ((g == 1) ? M1 : M2);
    int n0 = blockIdx.x * 64, k0 = blockIdx.y * 64;
    int c = threadIdx.x & 63, r4 = threadIdx.x >> 6;
#pragma unroll
    for (int i = 0; i < 16; ++i) {
        int k = r4 + i * 4;
        tile[k][c] = W[(size_t)(k0 + k) * D_ + n0 + c];
    }
    __syncthreads();
    _Float16* out = Mt + (size_t)g * D_ * DINc;
#pragma unroll
    for (int i = 0; i < 16; ++i) {
        int n = r4 + i * 4;
        out[(size_t)(n0 + n) * DINc + k0 + c] = (_Float16)tile[c][n];
    }
}

// ---------------- mask transpose: maskT[t][b] = (float) mask[b][t] ----------------
__global__ __launch_bounds__(256) void k_cvtM(const int* __restrict__ mask, float* __restrict__ maskT) {
    int idx = blockIdx.x * 256 + threadIdx.x;   // 32768
    int t = idx >> 6, b = idx & 63;
    maskT[idx] = (float)mask[(size_t)b * T_ + t];
}

// ---- input projections: xprojT[g][t][n][b] = (Xh[m] @ W_g)[n] + b_g[n], m=t*64+b (f16) ----
__global__ __launch_bounds__(256) void k_gemm(const _Float16* __restrict__ Xh, const _Float16* __restrict__ Wt,
                                              const float* __restrict__ bz, const float* __restrict__ br,
                                              const float* __restrict__ bh, _Float16* __restrict__ xprojT) {
    __shared__ _Float16 As[128 * 32];
    __shared__ _Float16 Bs[128 * 32];
    int g = blockIdx.z;
    const _Float16* Wg = Wt + (size_t)g * 512 * 512;
    const float* bias = (g == 0) ? bz : ((g == 1) ? br : bh);
    _Float16* out = xprojT + (size_t)g * 16777216;
    int mb = blockIdx.x * 128, nb = blockIdx.y * 128;
    int tid = threadIdx.x, l = tid & 63, w = tid >> 6;
    int wr = w >> 1, wc = w & 1;
    int lr = l & 15, lg = l >> 4;

    floatx4 acc[4][4] = {};

    int ga0 = tid, ga1 = tid + 256;
    int ra0 = ga0 >> 2, ca0 = (ga0 & 3) * 8;
    int ra1 = ga1 >> 2, ca1 = (ga1 & 3) * 8;

    uint4 pa0, pa1, pb0, pb1;
    pa0 = *(const uint4*)(Xh + (size_t)(mb + ra0) * 512 + ca0);
    pa1 = *(const uint4*)(Xh + (size_t)(mb + ra1) * 512 + ca1);
    pb0 = *(const uint4*)(Wg + (size_t)(nb + ra0) * 512 + ca0);
    pb1 = *(const uint4*)(Wg + (size_t)(nb + ra1) * 512 + ca1);

    for (int kt = 0; kt < 16; ++kt) {
        __syncthreads();
        *(uint4*)(&As[ga0 * 8]) = pa0;
        *(uint4*)(&As[ga1 * 8]) = pa1;
        *(uint4*)(&Bs[ga0 * 8]) = pb0;
        *(uint4*)(&Bs[ga1 * 8]) = pb1;
        __syncthreads();
        if (kt < 15) {
            int kb = (kt + 1) * 32;
            pa0 = *(const uint4*)(Xh + (size_t)(mb + ra0) * 512 + kb + ca0);
            pa1 = *(const uint4*)(Xh + (size_t)(mb + ra1) * 512 + kb + ca1);
            pb0 = *(const uint4*)(Wg + (size_t)(nb + ra0) * 512 + kb + ca0);
            pb1 = *(const uint4*)(Wg + (size_t)(nb + ra1) * 512 + kb + ca1);
        }
        half8 af[4], bf[4];
#pragma unroll
        for (int mi = 0; mi < 4; mi++) af[mi] = *(const half8*)(&As[(wr * 64 + mi * 16 + lr) * 32 + lg * 8]);
#pragma unroll
        for (int ni = 0; ni < 4; ni++) bf[ni] = *(const half8*)(&Bs[(wc * 64 + ni * 16 + lr) * 32 + lg * 8]);
#pragma unroll
        for (int mi = 0; mi < 4; mi++)
#pragma unroll
            for (int ni = 0; ni < 4; ni++)
                acc[mi][ni] = __builtin_amdgcn_mfma_f32_16x16x32_f16(af[mi], bf[ni], acc[mi][ni], 0, 0, 0);
    }

#pragma unroll
    for (int ni = 0; ni < 4; ni++) {
        int col = nb + wc * 64 + ni * 16 + lr;
        float bv = bias[col];
#pragma unroll
        for (int mi = 0; mi < 4; mi++) {
            int row = mb + wr * 64 + mi * 16 + lg * 4;
            int tt = row >> 6, bb = row & 63;
            half4 hv;
#pragma unroll
            for (int i = 0; i < 4; i++) hv[i] = (_Float16)(acc[mi][ni][i] + bv);
            *(half4*)(out + (size_t)tt * 32768 + (size_t)col * 64 + bb) = hv;
        }
    }
}

// -------- agent-scope (device-coherent) primitives — PROVEN path (Round 2) --------
__device__ __forceinline__ void st_agent(unsigned long long* p, unsigned long long v) {
    __hip_atomic_store(p, v, __ATOMIC_RELAXED, __HIP_MEMORY_SCOPE_AGENT);
}
__device__ __forceinline__ unsigned ld_flag(const unsigned* p) {
    return __hip_atomic_load(p, __ATOMIC_RELAXED, __HIP_MEMORY_SCOPE_AGENT);
}
__device__ __forceinline__ void st_flag(unsigned* p, unsigned v) {
    __hip_atomic_store(p, v, __ATOMIC_RELAXED, __HIP_MEMORY_SCOPE_AGENT);
}
// 16B agent-scope load, NO wait (caller fences with a single vmcnt(0))
__device__ __forceinline__ uintx4 ld16_agent(const void* p) {
    uintx4 r;
    asm volatile("global_load_dwordx4 %0, %1, off sc0 sc1" : "=v"(r) : "v"(p) : "memory");
    return r;
}

// pack this thread's 4 fp32 values (4 rows, 1 col) into the 8B row-major unit
// (1 row, 4 cols) for its assigned row (lr&3), via 2-round shfl_xor butterfly
__device__ __forceinline__ unsigned long long pack_quad(const float v4[4], int lr) {
    unsigned long long unit = 0;
    int j = lr & 3;
#pragma unroll
    for (int i = 0; i < 4; i++) {
        _Float16 hv = (_Float16)v4[i];
        unsigned int v = (unsigned int)__builtin_bit_cast(unsigned short, hv);
        unsigned int o1 = __shfl_xor(v, 1, 64);
        unsigned int pair = (lr & 1) ? (o1 | (v << 16)) : (v | (o1 << 16));
        unsigned int q2 = __shfl_xor(pair, 2, 64);
        unsigned long long u = (lr & 2) ? ((unsigned long long)q2 | ((unsigned long long)pair << 32))
                                        : ((unsigned long long)pair | ((unsigned long long)q2 << 32));
        if (i == j) unit = u;
    }
    return unit;
}

// ---------------- recurrent scan: 16 WGs x 512 threads, each owns JS=32 columns ----------------
__global__ __launch_bounds__(512, 2) void k_scan(const _Float16* __restrict__ Ut,      // [3][n][k] f16
                                                 const float* __restrict__ maskT,
                                                 const _Float16* __restrict__ xprojT,
                                                 unsigned long long* __restrict__ hbuf,   // [2][64][128] u64
                                                 unsigned long long* __restrict__ rhbuf,  // [2][64][128] u64
                                                 unsigned* __restrict__ fh, unsigned* __restrict__ fr,
                                                 float* __restrict__ out) {
    __shared__ __align__(16) _Float16 Ulds[2 * JS * 512];   // 64KB: Uz,Ur [n][k] swizzled
    __shared__ __align__(16) _Float16 Stg[64 * 512];        // 64KB: exchange staging, swizzled
    char* StgB = (char*)Stg;
    int tid = threadIdx.x, l = tid & 63, w = tid >> 6;
    int lr = l & 15, lg = l >> 4;
    int mt = w >> 1, nt = w & 1;              // wave's (M,N) 16x16 tile
    int slot = blockIdx.x;
    int jsb = slot * JS;

    // ---- stage Uz, Ur into LDS (already transposed f16; add XOR swizzle) ----
    for (int c = tid; c < 2 * JS * 64; c += 512) {     // 16B chunks: 2 gates x 32 n x 64 chunks
        int g  = c >> 11;
        int n  = (c >> 6) & 31;
        int k16 = c & 63;
        uintx4 v = *(const uintx4*)(Ut + (size_t)g * 262144 + (size_t)(jsb + n) * 512 + k16 * 8);
        *(uintx4*)((char*)Ulds + g * 32768 + n * 1024 + ((k16 * 16) ^ ((n & 7) << 4))) = v;
    }
    // ---- preload U_h fragments into registers (static across t) ----
    half8 uhf[16];
    {
        const _Float16* UtH = Ut + (size_t)2 * 262144;
        int ncol = jsb + nt * 16 + lr;
#pragma unroll
        for (int j = 0; j < 16; j++)
            uhf[j] = *(const half8*)(UtH + (size_t)ncol * 512 + j * 32 + lg * 8);
    }
    __syncthreads();

    const char* UB = (const char*)Ulds + (nt * 16 + lr) * 1024;  // B-row base for Uz (Ur at +32KB)
    const int swz = (lr & 7) << 4;

    int row0 = mt * 16 + lg * 4;              // this thread's 4 C-rows (batch)
    int colg = jsb + nt * 16 + lr;            // this thread's C-col (global hidden index)

    float h4[4]  = {0.f, 0.f, 0.f, 0.f};
    float hm4[4] = {0.f, 0.f, 0.f, 0.f};

    const int punit = (mt * 16 + lg * 4 + (lr & 3)) * 128 + ((jsb + nt * 16) >> 2) + ((lr >> 2) & 3);
    const char* SB = StgB + (mt * 16 + lr) * 1024;    // A-frag row base in staging

    const _Float16* xzB = xprojT + (size_t)colg * 64 + row0;
    const _Float16* xrB = xzB + (size_t)16777216;
    const _Float16* xhB = xrB + (size_t)16777216;

    // ---------------- step 0: hm = 0, pure local ----------------
    {
        half4 xz0 = *(const half4*)(xzB);
        half4 xh0 = *(const half4*)(xhB);
        float4 m0 = *(const float4*)(maskT + row0);
#pragma unroll
        for (int i = 0; i < 4; i++) {
            float z  = 1.f / (1.f + __expf(-(float)xz0[i]));
            float hh = tanhf((float)xh0[i]);
            h4[i]  = (1.f - z) * hh;
            hm4[i] = ((float)m0[i]) * h4[i];
        }
        st_agent(hbuf + punit, pack_quad(hm4, lr));   // parity 0
        asm volatile("s_waitcnt vmcnt(0)" ::: "memory");
        __syncthreads();
        if (tid == 0) st_flag(fh + slot * 16, 1u);
    }

    for (int t = 1; t < T_; ++t) {
        const char* hmG = (const char*)(hbuf + ((t - 1) & 1) * 8192);
        char*       rhG = (char*)(rhbuf + (t & 1) * 8192);
        unsigned long long* rhW = rhbuf + (t & 1) * 8192;
        unsigned long long* hW  = hbuf + (t & 1) * 8192;

        // issue this step's x loads early
        half4 xzp = *(const half4*)(xzB + (size_t)t * 32768);
        half4 xrp = *(const half4*)(xrB + (size_t)t * 32768);
        half4 xhp = *(const half4*)(xhB + (size_t)t * 32768);
        float4 mv = *(const float4*)(maskT + (size_t)t * 64 + row0);

        // ================= phase 1: z, r =================
        if (w == 0) {
            for (;;) {
                unsigned v = (l < NWG) ? ld_flag(fh + l * 16) : (unsigned)t;
                if (__all(v >= (unsigned)t)) break;
            }
        }
        __syncthreads();
        // gather hm (wave w covers rows w*8..w*8+7), 16B coalesced sc1 loads -> LDS swizzled
        {
            uintx4 gg[8];
#pragma unroll
            for (int it = 0; it < 8; ++it)
                gg[it] = ld16_agent(hmG + (w * 8 + it) * 1024 + l * 16);
            asm volatile("s_waitcnt vmcnt(0)" ::: "memory");
#pragma unroll
            for (int it = 0; it < 8; ++it)
                *(uintx4*)(StgB + (w * 8 + it) * 1024 + ((l * 16) ^ (it << 4))) = gg[it];
        }
        __syncthreads();
        half8 af[16];
#pragma unroll
        for (int j = 0; j < 16; j++)
            af[j] = *(const half8*)(SB + ((j * 64 + lg * 16) ^ swz));
        floatx4 accz = {0.f, 0.f, 0.f, 0.f}, accr = {0.f, 0.f, 0.f, 0.f};
#pragma unroll
        for (int j = 0; j < 16; j++) {
            int boff = (j * 64 + lg * 16) ^ swz;
            half8 bz8 = *(const half8*)(UB + boff);
            half8 br8 = *(const half8*)(UB + 32768 + boff);
            accz = __builtin_amdgcn_mfma_f32_16x16x32_f16(af[j], bz8, accz, 0, 0, 0);
            accr = __builtin_amdgcn_mfma_f32_16x16x32_f16(af[j], br8, accr, 0, 0, 0);
        }
        float z4[4], rh4[4];
#pragma unroll
        for (int i = 0; i < 4; i++) {
            float zz = 1.f / (1.f + __expf(-((float)xzp[i] + accz[i])));
            float rr = 1.f / (1.f + __expf(-((float)xrp[i] + accr[i])));
            z4[i]  = zz;
            rh4[i] = rr * hm4[i];
        }
        st_agent(rhW + punit, pack_quad(rh4, lr));
        asm volatile("s_waitcnt vmcnt(0)" ::: "memory");
        __syncthreads();
        if (tid == 0) st_flag(fr + slot * 16, (unsigned)t);

        // ================= phase 2: candidate + update =================
        if (w == 0) {
            for (;;) {
                unsigned v = (l < NWG) ? ld_flag(fr + l * 16) : (unsigned)t;
                if (__all(v >= (unsigned)t)) break;
            }
        }
        __syncthreads();
        {
            uintx4 gg[8];
#pragma unroll
            for (int it = 0; it < 8; ++it)
                gg[it] = ld16_agent(rhG + (w * 8 + it) * 1024 + l * 16);
            asm volatile("s_waitcnt vmcnt(0)" ::: "memory");
#pragma unroll
            for (int it = 0; it < 8; ++it)
                *(uintx4*)(StgB + (w * 8 + it) * 1024 + ((l * 16) ^ (it << 4))) = gg[it];
        }
        __syncthreads();
        half8 af2[16];
#pragma unroll
        for (int j = 0; j < 16; j++)
            af2[j] = *(const half8*)(SB + ((j * 64 + lg * 16) ^ swz));
        floatx4 acch0 = {0.f, 0.f, 0.f, 0.f}, acch1 = {0.f, 0.f, 0.f, 0.f};
#pragma unroll
        for (int j = 0; j < 16; j += 2) {
            acch0 = __builtin_amdgcn_mfma_f32_16x16x32_f16(af2[j],     uhf[j],     acch0, 0, 0, 0);
            acch1 = __builtin_amdgcn_mfma_f32_16x16x32_f16(af2[j + 1], uhf[j + 1], acch1, 0, 0, 0);
        }
#pragma unroll
        for (int i = 0; i < 4; i++) {
            float hh = tanhf((float)xhp[i] + acch0[i] + acch1[i]);
            h4[i]  = z4[i] * hm4[i] + (1.f - z4[i]) * hh;
            hm4[i] = ((float)mv[i]) * h4[i];
        }
        st_agent(hW + punit, pack_quad(hm4, lr));
        asm volatile("s_waitcnt vmcnt(0)" ::: "memory");
        __syncthreads();
        if (tid == 0) st_flag(fh + slot * 16, (unsigned)(t + 1));
    }

#pragma unroll
    for (int i = 0; i < 4; i++)
        out[(size_t)(row0 + i) * 512 + colg] = h4[i];
}

extern "C" void kernel_launch(void* const* d_in, const int* in_sizes, int n_in,
                              void* d_out, int out_size, void* d_ws, size_t ws_size,
                              hipStream_t stream) {
    (void)in_sizes; (void)n_in; (void)out_size; (void)ws_size;
    const float* X  = (const float*)d_in[0];
    const float* Wz = (const float*)d_in[1];
    const float* Uz = (const float*)d_in[2];
    const float* bz = (const float*)d_in[3];
    const float* Wr = (const float*)d_in[4];
    const float* Ur = (const float*)d_in[5];
    const float* br = (const float*)d_in[6];
    const float* Wh = (const float*)d_in[7];
    const float* Uh = (const float*)d_in[8];
    const float* bh = (const float*)d_in[9];
    const int* mask = (const int*)d_in[10];
    float* out = (float*)d_out;

    char* ws = (char*)d_ws;
    unsigned* fh = (unsigned*)ws;                                    // 1KB (16 flags, 64B stride)
    unsigned* fr = (unsigned*)(ws + 1024);                           // 1KB
    unsigned long long* hbuf  = (unsigned long long*)(ws + 8192);              // 128KB [2][64][128]
    unsigned long long* rhbuf = (unsigned long long*)(ws + 8192 + 131072);     // 128KB
    _Float16* Xh     = (_Float16*)(ws + 8192 + 2 * 131072);                    // 32MB
    _Float16* Wt     = (_Float16*)(ws + 8192 + 2 * 131072 + 33554432);         // 1.5MB
    _Float16* Ut     = (_Float16*)(ws + 8192 + 2 * 131072 + 33554432 + 1572864);           // 1.5MB
    _Float16* xprojT = (_Float16*)(ws + 8192 + 2 * 131072 + 33554432 + 2 * 1572864);       // 96MB
    float*    maskT  = (float*)(ws + 8192 + 2 * 131072 + 33554432 + 2 * 1572864 + 100663296); // 128KB

    hipMemsetAsync(ws, 0, 8192, stream);
    hipLaunchKernelGGL(k_cvtX, dim3(8192), dim3(256), 0, stream, X, Xh);
    hipLaunchKernelGGL(k_cvtW, dim3(8, 8, 3), dim3(256), 0, stream, Wz, Wr, Wh, Wt);
    hipLaunchKernelGGL(k_cvtW, dim3(8, 8, 3), dim3(256), 0, stream, Uz, Ur, Uh, Ut);
    hipLaunchKernelGGL(k_cvtM, dim3(128), dim3(256), 0, stream, mask, maskT);
    hipLaunchKernelGGL(k_gemm, dim3(256, 4, 3), dim3(256), 0, stream, Xh, Wt, bz, br, bh, xprojT);
    hipLaunchKernelGGL(k_scan, dim3(NWG), dim3(512), 0, stream, Ut, maskT, xprojT,
                       hbuf, rhbuf, fh, fr, out);
}